// Round 9
// baseline (50.565 us; speedup 1.0000x reference)
//
#include <hip/hip_runtime.h>

// Conv2D 3x3 VALID NHWC, B=16 H=W=224 C=32 F=32 -> [16,222,222,32] fp32.
// im2col GEMM M=788544 K=288 N=32, bf16 MFMA 16x16x32 (swapped: D[filt][pix]).
// Round 9: R8's compute phase was LDS-read + perm bound (288 wave-b128/tile,
// 72 perms/lane/tile redone per tap). Add a bf16 ring converted ONCE per
// pixel, with the convert running CONCURRENTLY with compute 2 tiles ahead
// (between the same barriers) -- R7 showed a serial convert phase loses;
// this placement adds zero barriers.
//  - fp32 stage ring: 2 chunks x 4 rows x 9216 B = 73.7 KB
//  - bf16 ring: 16 rows x 5280 B = 84.5 KB (80 B/px -> conflict-benign b128)
//  - compute tap = 1 ds_read_b128, no perms (was 2 reads + 4 perms)
//  - lgkmcnt(0) before closing raw barrier (ds_writes must drain; raw
//    s_barrier does not wait counters).

#define HO 222
#define WO 222
#define HIN 224
#define WIN 224
#define CIN 32
#define FOUT 32

#define TW 64                  // output cols per block
#define IC 66                  // staged cols
#define NT 14                  // tiles per block (4 rows each)
#define GROWS 56               // output rows per block
#define NCHUNK 15              // 4-row stage chunks
#define ROWB 9216              // fp32 padded row bytes (576 granules, 528 data)
#define BROWB 5280             // bf16 row bytes (66 px * 80 B)
#define BRB 16                 // bf16 ring rows (slot = row & 15)
#define CVT_ITEMS (4 * IC * 4) // 1056 convert items per chunk

typedef __attribute__((ext_vector_type(8))) short short8;
typedef __attribute__((ext_vector_type(4))) float float4v;

__device__ inline short f2bf(float f) {                  // RNE (weights only)
    unsigned u = __builtin_bit_cast(unsigned, f);
    unsigned r = (u + 0x7FFFu + ((u >> 16) & 1u)) >> 16;
    return (short)r;
}

__global__ __launch_bounds__(512, 2) void conv3x3_mfma(
    const float* __restrict__ x,     // [16,224,224,32]
    const float* __restrict__ w,     // [32][288 = (kh,kw,c)]
    const float* __restrict__ bias,  // [32]
    float* __restrict__ out)         // [16,222,222,32]
{
    __shared__ uint4 lds_f32[(8 * ROWB) / 16];      // 73728 B: 2 chunks x 4 rows
    __shared__ uint4 lds_b16[(BRB * BROWB) / 16];   // 84480 B: 16 bf16 rows
    __shared__ uint4 lds_slack[64];                 // 1024 B dump
    char* f32c = reinterpret_cast<char*>(lds_f32);
    char* b16c = reinterpret_cast<char*>(lds_b16);
    char* slackc = reinterpret_cast<char*>(lds_slack);

    const int wot = blockIdx.x;            // 0..3
    const int g   = blockIdx.y;            // 0..3 row groups
    const int b   = blockIdx.z;            // 0..15
    const int wo_base = wot * TW;
    const int gr0 = g * GROWS;

    const int tid  = threadIdx.x;
    const int lane = tid & 63;
    const int wave = tid >> 6;             // 0..7

    const int fcol = lane & 15;            // A row (filter) / D col (pixel)
    const int kq   = lane >> 4;            // k-slice: k = kq*8 + i

    // ---- weights -> register A-fragments (loads drained by compiler's
    //      waitcnt before first f2bf use, i.e. before any STAGE issues) ----
    short8 bfr[2][9];
#pragma unroll
    for (int h = 0; h < 2; ++h) {
        const float* wf = w + (h * 16 + fcol) * 288 + kq * 8;
#pragma unroll
        for (int s = 0; s < 9; ++s) {
            float4 lo = reinterpret_cast<const float4*>(wf + s * 32)[0];
            float4 hi = reinterpret_cast<const float4*>(wf + s * 32)[1];
            short8 v;
            v[0] = f2bf(lo.x); v[1] = f2bf(lo.y); v[2] = f2bf(lo.z); v[3] = f2bf(lo.w);
            v[4] = f2bf(hi.x); v[5] = f2bf(hi.y); v[6] = f2bf(hi.z); v[7] = f2bf(hi.w);
            bfr[h][s] = v;
        }
    }
    const float4 bias0 = reinterpret_cast<const float4*>(bias)[kq];
    const float4 bias1 = reinterpret_cast<const float4*>(bias)[4 + kq];

    // ---- stage chunk k (4 input rows) into fp32 slot k&1; uniform 5
    //      gload_lds/wave; waves 2j,2j+1 own row j; seg 9 -> slack ----
    auto STAGE = [&](int k) {
        const int j    = wave >> 1;
        const int half = wave & 1;
        int ir = gr0 + 4 * k + j; if (ir > HIN - 1) ir = HIN - 1;
        char* rowbase = f32c + (((k & 1) << 2) + j) * ROWB;
#pragma unroll
        for (int i = 0; i < 5; ++i) {
            const int seg  = half + 2 * i;           // 0..9 uniform per wave
            const int gidr = seg * 64 + lane;
            int c = gidr >> 3; if (c > IC - 1) c = IC - 1;
            const int gsub = (gidr & 7) ^ (c & 7);   // pre-swizzled source
            int icl = wo_base + c; if (icl > WIN - 1) icl = WIN - 1;
            const float* src = x + ((b * HIN + ir) * WIN + icl) * CIN + gsub * 4;
            char* dst = (seg < 9 ? rowbase + seg * 1024 : slackc) + lane * 16;
            __builtin_amdgcn_global_load_lds(
                (const __attribute__((address_space(1))) void*)src,
                (__attribute__((address_space(3))) void*)dst,
                16, 0, 0);
        }
    };

    // ---- convert chunk cn: fp32 slot (cn&1) -> bf16 ring rows (4cn..+3)&15,
    //      once per pixel (truncation pack; 2 b128 reads + 4 perms + 1 write) ----
    auto CONVERT = [&](int cn) {
        const char* fb = f32c + ((cn & 1) << 2) * ROWB;
#pragma unroll
        for (int i = 0; i < 3; ++i) {
            int id = tid + i * 512;
            if (id < CVT_ITEMS) {
                int p   = id >> 2;                   // 0..263
                int kp  = id & 3;                    // 8-ch group
                int row = p / IC;
                int col = p - row * IC;
                int key = col & 7;
                const char* px = fb + row * ROWB + col * 128;
                const uint4 ua = *reinterpret_cast<const uint4*>(
                    px + (((2 * kp) ^ key) << 4));       // ch 8kp..+3
                const uint4 ub = *reinterpret_cast<const uint4*>(
                    px + (((2 * kp + 1) ^ key) << 4));   // ch 8kp+4..+7
                unsigned w0 = __builtin_amdgcn_perm(ua.y, ua.x, 0x07060302u);
                unsigned w1 = __builtin_amdgcn_perm(ua.w, ua.z, 0x07060302u);
                unsigned w2 = __builtin_amdgcn_perm(ub.y, ub.x, 0x07060302u);
                unsigned w3 = __builtin_amdgcn_perm(ub.w, ub.z, 0x07060302u);
                uint4 pk = {w0, w1, w2, w3};
                const int brow = (4 * cn + row) & (BRB - 1);
                *reinterpret_cast<uint4*>(
                    b16c + brow * BROWB + col * 80 + kp * 16) = pk;
            }
        }
    };

    // ---------- prologue: convert chunks 0,1; chunks 2,3 in flight ----------
    STAGE(0); STAGE(1);
    asm volatile("s_waitcnt vmcnt(0)" ::: "memory");
    __builtin_amdgcn_sched_barrier(0);
    __builtin_amdgcn_s_barrier();
    __builtin_amdgcn_sched_barrier(0);
    CONVERT(0); CONVERT(1);
    asm volatile("s_waitcnt lgkmcnt(0)" ::: "memory");
    __builtin_amdgcn_sched_barrier(0);
    __builtin_amdgcn_s_barrier();
    __builtin_amdgcn_sched_barrier(0);
    STAGE(2); STAGE(3);

#pragma unroll 1
    for (int t = 0; t < NT; ++t) {
        // retire chunk t+2's loads; keep chunk t+3 (5/wave) in flight
        if (t + 3 < NCHUNK) asm volatile("s_waitcnt vmcnt(5)" ::: "memory");
        else                asm volatile("s_waitcnt vmcnt(0)" ::: "memory");
        __builtin_amdgcn_sched_barrier(0);
        __builtin_amdgcn_s_barrier();
        __builtin_amdgcn_sched_barrier(0);

        // convert 2 tiles ahead (writes bf16 slots disjoint from compute reads)
        if (t + 2 < NCHUNK) CONVERT(t + 2);

        const int rbase = 4 * t;               // tile's first input row (rel)

#pragma unroll
        for (int j = 0; j < 2; ++j) {
            const int chunk = wave * 2 + j;    // 16 chunks of 16 pixels
            const int pix = chunk * 16 + fcol;
            const int hoo = pix >> 6;          // 0..3
            const int woo = pix & 63;

            float4v acc0 = {0.f, 0.f, 0.f, 0.f};
            float4v acc1 = {0.f, 0.f, 0.f, 0.f};
#pragma unroll
            for (int s = 0; s < 9; ++s) {
                const int kh = s / 3, kw = s % 3;
                const int slot = (rbase + hoo + kh) & (BRB - 1);
                const short8 a = *reinterpret_cast<const short8*>(
                    b16c + slot * BROWB + (woo + kw) * 80 + kq * 16);
                acc0 = __builtin_amdgcn_mfma_f32_16x16x32_bf16(bfr[0][s], a, acc0, 0, 0, 0);
                acc1 = __builtin_amdgcn_mfma_f32_16x16x32_bf16(bfr[1][s], a, acc1, 0, 0, 0);
            }

            // D[filter][pixel]: col(lane&15)=pixel, row=kq*4+r=filter
            const int ho = gr0 + rbase + hoo;
            const int wo = wo_base + woo;
            if (ho < HO && wo < WO) {
                float* o = out + ((b * HO + ho) * WO + wo) * FOUT;
                float4 v0 = {acc0[0] + bias0.x, acc0[1] + bias0.y,
                             acc0[2] + bias0.z, acc0[3] + bias0.w};
                float4 v1 = {acc1[0] + bias1.x, acc1[1] + bias1.y,
                             acc1[2] + bias1.z, acc1[3] + bias1.w};
                reinterpret_cast<float4*>(o)[kq]     = v0;
                reinterpret_cast<float4*>(o)[4 + kq] = v1;
            }
        }

        // drain convert ds_writes, then publish; next STAGE reuses the fp32
        // slot convert just finished reading.
        asm volatile("s_waitcnt lgkmcnt(0)" ::: "memory");
        __builtin_amdgcn_sched_barrier(0);
        __builtin_amdgcn_s_barrier();
        __builtin_amdgcn_sched_barrier(0);

        if (t + 4 < NCHUNK) STAGE(t + 4);
    }
}

extern "C" void kernel_launch(void* const* d_in, const int* in_sizes, int n_in,
                              void* d_out, int out_size, void* d_ws, size_t ws_size,
                              hipStream_t stream) {
    const float* x    = (const float*)d_in[0];
    const float* w    = (const float*)d_in[1];
    const float* bias = (const float*)d_in[2];
    float* out        = (float*)d_out;

    dim3 grid(4, 4, 16);    // col-tile, row-group (56 rows), batch = 256 blocks
    dim3 block(512);
    conv3x3_mfma<<<grid, block, 0, stream>>>(x, w, bias, out);
}